// Round 2
// baseline (38625.977 us; speedup 1.0000x reference)
//
#include <hip/hip_runtime.h>

#define T_STEPS 65536
#define NIN 99
#define HID 64
#define G4 256   // 4*HID gates
#define TS 128   // timesteps per block in the projection kernel
#define PF 8     // prefetch depth (steps) in the recurrence kernel

__device__ __forceinline__ float frcp(float x) { return __builtin_amdgcn_rcpf(x); }
__device__ __forceinline__ float fexp(float x) { return __expf(x); }
__device__ __forceinline__ float sigmoid_f(float x) { return frcp(1.0f + fexp(-x)); }
__device__ __forceinline__ float tanh_f(float x) {
    float ax = fabsf(x);
    float e  = fexp(2.0f * ax);                 // inf for large ax fine: rcp(inf)=0
    float r  = 1.0f - 2.0f * frcp(e + 1.0f);
    return copysignf(r, x);
}
// wave-uniform broadcast of lane `lane`'s value via readlane (VALU, not LDS pipe)
__device__ __forceinline__ float bcast(float v, int lane) {
    return __int_as_float(__builtin_amdgcn_readlane(__float_as_int(v), lane));
}

// ---------------- Kernel 1: xz[t][g] = W_ih[g] . x[t] + b_ih[g] + b_hh[g] ----------------
__global__ __launch_bounds__(256) void xz_kernel(
    const float* __restrict__ x, const float* __restrict__ W_ih,
    const float* __restrict__ b_ih, const float* __restrict__ b_hh,
    float* __restrict__ xz) {
    __shared__ __align__(16) float xs[TS * 100];   // padded rows: 400 B stride, 16B-aligned
    const int g  = threadIdx.x;
    const int t0 = blockIdx.x * TS;

    // stage x tile (contiguous in global) into padded LDS rows
    for (int i = g; i < TS * NIN; i += 256) {
        int tl = i / NIN;
        int j  = i - tl * NIN;
        xs[tl * 100 + j] = x[(size_t)t0 * NIN + i];
    }

    // this gate's W_ih row in registers (one-time, cached reads)
    float w[NIN];
#pragma unroll
    for (int j = 0; j < NIN; ++j) w[j] = W_ih[g * NIN + j];
    const float bias = b_ih[g] + b_hh[g];
    __syncthreads();

    for (int tl = 0; tl < TS; ++tl) {
        const float* xr = &xs[tl * 100];
        float a0 = bias, a1 = 0.f, a2 = 0.f, a3 = 0.f;
#pragma unroll
        for (int j4 = 0; j4 < 24; ++j4) {          // 96 of 99 via broadcast b128
            float4 xv = *(const float4*)(xr + 4 * j4);
            a0 = fmaf(w[4 * j4 + 0], xv.x, a0);
            a1 = fmaf(w[4 * j4 + 1], xv.y, a1);
            a2 = fmaf(w[4 * j4 + 2], xv.z, a2);
            a3 = fmaf(w[4 * j4 + 3], xv.w, a3);
        }
        a0 = fmaf(w[96], xr[96], a0);
        a1 = fmaf(w[97], xr[97], a1);
        a2 = fmaf(w[98], xr[98], a2);
        xz[(size_t)(t0 + tl) * G4 + g] = (a0 + a1) + (a2 + a3);
    }
}

// ---------------- Kernel 2: sequential LSTM recurrence + MLP head (single block) ----------------
// Layout: 4 waves; wave w, lane l computes gate row g = 64w+l.
// Every wave redundantly keeps h[l], c[l] in lane-l registers, so the matvec
// broadcasts h via v_readlane (VALU) instead of LDS reads. One barrier/step,
// double-buffered gate exchange.
__global__ __launch_bounds__(256) void lstm_kernel(
    const float* __restrict__ xz, const float* __restrict__ W_hh,
    const float* __restrict__ W1, const float* __restrict__ W2,
    const float* __restrict__ b2, float* __restrict__ out) {
    __shared__ float gbuf[2][G4];
    __shared__ float hfin[HID];
    __shared__ float hbuf[32];
    const int tid = threadIdx.x;
    const int l   = tid & 63;
    const int wv  = tid >> 6;

    // gate-row weights in VGPRs
    float wr[HID];
#pragma unroll
    for (int j = 0; j < HID; ++j) wr[j] = W_hh[tid * HID + j];

    float h = 0.0f, c = 0.0f;      // lane l of every wave: h[l], c[l] (redundant copies)

    const float* zp = xz + tid;    // coalesced column of xz
    float zcur[PF], znxt[PF];
#pragma unroll
    for (int p = 0; p < PF; ++p) { zcur[p] = zp[(size_t)p * G4]; znxt[p] = 0.0f; }

    const bool tanh_gate = (wv == 2);   // gate 'g' block

    for (int tb = 0; tb < T_STEPS; tb += PF) {
        if (tb + PF < T_STEPS) {
#pragma unroll
            for (int p = 0; p < PF; ++p) znxt[p] = zp[(size_t)(tb + PF + p) * G4];
        }
#pragma unroll
        for (int u = 0; u < PF; ++u) {
            // z_g = xz[t][g] + W_hh[g] . h  via readlane broadcast, 4-way ILP
            float a0 = zcur[u], a1 = 0.f, a2 = 0.f, a3 = 0.f;
#pragma unroll
            for (int j = 0; j < HID; j += 4) {
                a0 = fmaf(wr[j + 0], bcast(h, j + 0), a0);
                a1 = fmaf(wr[j + 1], bcast(h, j + 1), a1);
                a2 = fmaf(wr[j + 2], bcast(h, j + 2), a2);
                a3 = fmaf(wr[j + 3], bcast(h, j + 3), a3);
            }
            float z = (a0 + a1) + (a2 + a3);
            float a = tanh_gate ? tanh_f(z) : sigmoid_f(z);

            float* buf = gbuf[u & 1];
            buf[tid] = a;
            __syncthreads();
            float iv = buf[l];
            float fv = buf[64 + l];
            float gv = buf[128 + l];
            float ov = buf[192 + l];
            c = fmaf(fv, c, iv * gv);
            h = ov * tanh_f(c);
        }
#pragma unroll
        for (int p = 0; p < PF; ++p) zcur[p] = znxt[p];
    }

    // head: out = W2 @ relu(W1 @ relu(h_T)) + b2
    if (tid < HID) hfin[tid] = h;
    __syncthreads();
    if (tid < 32) {
        float s = 0.0f;
#pragma unroll
        for (int j = 0; j < HID; ++j) s += W1[tid * HID + j] * fmaxf(hfin[j], 0.0f);
        hbuf[tid] = fmaxf(s, 0.0f);
    }
    __syncthreads();
    if (tid < 3) {
        float s = b2[tid];
#pragma unroll
        for (int j = 0; j < 32; ++j) s += W2[tid * 32 + j] * hbuf[j];
        out[tid] = s;
    }
}

extern "C" void kernel_launch(void* const* d_in, const int* in_sizes, int n_in,
                              void* d_out, int out_size, void* d_ws, size_t ws_size,
                              hipStream_t stream) {
    const float* x   = (const float*)d_in[0];
    const float* Wih = (const float*)d_in[1];
    const float* Whh = (const float*)d_in[2];
    const float* bih = (const float*)d_in[3];
    const float* bhh = (const float*)d_in[4];
    const float* W1  = (const float*)d_in[5];
    const float* W2  = (const float*)d_in[6];
    const float* b2  = (const float*)d_in[7];
    float* out = (float*)d_out;
    float* xz  = (float*)d_ws;   // T_STEPS * 256 floats = 64 MB

    xz_kernel<<<T_STEPS / TS, 256, 0, stream>>>(x, Wih, bih, bhh, xz);
    lstm_kernel<<<1, 256, 0, stream>>>(xz, Whh, W1, W2, b2, out);
}